// Round 1
// baseline (765.465 us; speedup 1.0000x reference)
//
#include <hip/hip_runtime.h>

#define NN 20000
#define EE 320000
#define EF 340000   /* EE + NN self loops */
#define EDIM 22

// ---------------------------------------------------------------------------
// Setup: CSR by dst (counting sort), mean edge_attr for self loops
// ---------------------------------------------------------------------------

__global__ void count_deg_kernel(const int* __restrict__ dst, int* __restrict__ cnt) {
  int e = blockIdx.x * blockDim.x + threadIdx.x;
  if (e < EE) atomicAdd(&cnt[dst[e]], 1);
}

// single-block scan of (cnt[i]+1) over NN elements -> exclusive offsets
__global__ void scan_kernel(const int* __restrict__ cnt, int* __restrict__ off,
                            int* __restrict__ cursor) {
  __shared__ int tmp[1024];
  __shared__ int carry;
  int tid = threadIdx.x;
  if (tid == 0) carry = 0;
  __syncthreads();
  for (int base = 0; base < NN; base += 1024) {
    int i = base + tid;
    int v = (i < NN) ? (cnt[i] + 1) : 0;
    tmp[tid] = v;
    __syncthreads();
    for (int s = 1; s < 1024; s <<= 1) {
      int t = (tid >= s) ? tmp[tid - s] : 0;
      __syncthreads();
      tmp[tid] += t;
      __syncthreads();
    }
    int excl = carry + tmp[tid] - v;
    if (i < NN) { off[i] = excl; cursor[i] = excl; }
    int tot = tmp[1023];
    __syncthreads();
    if (tid == 0) carry += tot;
    __syncthreads();
  }
  if (tid == 0) off[NN] = carry;
}

__global__ void scatter_kernel(const int* __restrict__ src, const int* __restrict__ dst,
                               int* __restrict__ cursor, int* __restrict__ csr_src,
                               int* __restrict__ csr_eid) {
  int e = blockIdx.x * blockDim.x + threadIdx.x;
  if (e >= EF) return;
  int s, d;
  if (e < EE) { s = src[e]; d = dst[e]; } else { s = e - EE; d = s; }
  int pos = atomicAdd(&cursor[d], 1);
  csr_src[pos] = s;
  csr_eid[pos] = e;
}

// mean of incoming edge_attr per node (self-loop fill value)
__global__ void mean_ea_kernel(const int* __restrict__ off, const int* __restrict__ csr_eid,
                               const int* __restrict__ cnt, const float* __restrict__ edge_attr,
                               float* __restrict__ mean_ea) {
  int t = blockIdx.x * blockDim.x + threadIdx.x;
  if (t >= NN * EDIM) return;
  int n = t / EDIM, d = t % EDIM;
  int s = off[n], e = off[n + 1];
  float sum = 0.f;
  for (int j = s; j < e; ++j) {
    int eid = csr_eid[j];
    if (eid < EE) sum += edge_attr[(size_t)eid * EDIM + d];
  }
  mean_ea[t] = sum / fmaxf((float)cnt[n], 1.f);
}

// ---------------------------------------------------------------------------
// f32 tiled GEMM: C[M,Nc] = A[M,K] @ B[K,Nc].  BM=BN=64, BK=16, 4x4 micro.
// K and Nc are multiples of 16/64 here (16|256 and 256|768).
// ---------------------------------------------------------------------------
__global__ __launch_bounds__(256) void gemm_kernel(
    const float* __restrict__ A, const float* __restrict__ B, float* __restrict__ C,
    int M, int K, int Nc) {
  __shared__ __align__(16) float As[16][64];  // As[k][m] (transposed A tile)
  __shared__ __align__(16) float Bs[16][64];  // Bs[k][n]
  const int tx = threadIdx.x & 15;
  const int ty = threadIdx.x >> 4;
  const int bm = blockIdx.y * 64;
  const int bn = blockIdx.x * 64;
  float acc[4][4] = {};
  for (int k0 = 0; k0 < K; k0 += 16) {
    // A tile: 64 rows x 16 cols, one float4 per thread
    {
      int r = threadIdx.x >> 2;          // 0..63
      int c4 = (threadIdx.x & 3) * 4;    // 0,4,8,12
      float4 v = make_float4(0.f, 0.f, 0.f, 0.f);
      if (bm + r < M)
        v = *reinterpret_cast<const float4*>(&A[(size_t)(bm + r) * K + k0 + c4]);
      As[c4 + 0][r] = v.x; As[c4 + 1][r] = v.y; As[c4 + 2][r] = v.z; As[c4 + 3][r] = v.w;
    }
    // B tile: 16 rows x 64 cols, one float4 per thread
    {
      int r = threadIdx.x >> 4;          // 0..15
      int c4 = (threadIdx.x & 15) * 4;   // 0..60
      float4 v = *reinterpret_cast<const float4*>(&B[(size_t)(k0 + r) * Nc + bn + c4]);
      *reinterpret_cast<float4*>(&Bs[r][c4]) = v;
    }
    __syncthreads();
#pragma unroll
    for (int k = 0; k < 16; ++k) {
      const float4 a4 = *reinterpret_cast<const float4*>(&As[k][ty * 4]);
      const float4 b4 = *reinterpret_cast<const float4*>(&Bs[k][tx * 4]);
      const float av[4] = {a4.x, a4.y, a4.z, a4.w};
      const float bv[4] = {b4.x, b4.y, b4.z, b4.w};
#pragma unroll
      for (int i = 0; i < 4; ++i)
#pragma unroll
        for (int j = 0; j < 4; ++j) acc[i][j] += av[i] * bv[j];
    }
    __syncthreads();
  }
#pragma unroll
  for (int i = 0; i < 4; ++i) {
    int r = bm + ty * 4 + i;
    if (r < M) {
      float4 o = make_float4(acc[i][0], acc[i][1], acc[i][2], acc[i][3]);
      *reinterpret_cast<float4*>(&C[(size_t)r * Nc + bn + tx * 4]) = o;
    }
  }
}

// ---------------------------------------------------------------------------
// a_s / a_d: [N,H] = sum_c h[n,h,c] * att
// ---------------------------------------------------------------------------
__global__ void asd_kernel(const float* __restrict__ h, const float* __restrict__ atts,
                           const float* __restrict__ attd, float* __restrict__ a_s,
                           float* __restrict__ a_d, int H, int C) {
  int t = blockIdx.x * blockDim.x + threadIdx.x;
  if (t >= NN * H) return;
  int n = t / H, hh = t % H;
  const float* row = &h[(size_t)n * H * C + hh * C];
  float s = 0.f, d = 0.f;
  for (int c = 0; c < C; ++c) {
    float v = row[c];
    s += v * atts[hh * C + c];
    d += v * attd[hh * C + c];
  }
  a_s[t] = s;
  a_d[t] = d;
}

// wecomb[d,h] = sum_c We[d, h*C+c] * att_e[h*C+c]   (pre-contraction of We)
__global__ void wecomb_kernel(const float* __restrict__ We, const float* __restrict__ atte,
                              float* __restrict__ wec, int H, int C) {
  int t = blockIdx.x * blockDim.x + threadIdx.x;
  if (t >= EDIM * H) return;
  int d = t / H, hh = t % H;
  float v = 0.f;
  for (int c = 0; c < C; ++c) v += We[(size_t)d * H * C + hh * C + c] * atte[hh * C + c];
  wec[t] = v;
}

// a_se[j,h] = a_e(edge j) + a_s[src(j),h], in CSR (dst-sorted) order
__global__ void ase_kernel(const int* __restrict__ csr_eid, const int* __restrict__ csr_src,
                           const float* __restrict__ edge_attr, const float* __restrict__ mean_ea,
                           const float* __restrict__ wec, const float* __restrict__ a_s,
                           float* __restrict__ a_se, int H) {
  int t = blockIdx.x * blockDim.x + threadIdx.x;
  if (t >= EF * H) return;
  int j = t / H, hh = t % H;
  int eid = csr_eid[j];
  const float* ea = (eid < EE) ? &edge_attr[(size_t)eid * EDIM]
                               : &mean_ea[(size_t)(eid - EE) * EDIM];
  float v = 0.f;
#pragma unroll
  for (int d = 0; d < EDIM; ++d) v += ea[d] * wec[d * H + hh];
  a_se[t] = v + a_s[csr_src[j] * H + hh];
}

// ---------------------------------------------------------------------------
// Per-node aggregation: one wave per node. Segment softmax + weighted gather.
// PERLANE=true : H*C=256, lane owns f = lane*4+k  (one head per lane, float4)
// PERLANE=false: H*C=768, lane owns f = k*64+lane (head = k, compile-time)
// ---------------------------------------------------------------------------
template <int H, int C, int KC, bool PERLANE>
__global__ __launch_bounds__(256) void gat_aggregate_kernel(
    const float* __restrict__ a_se, const float* __restrict__ a_d,
    const float* __restrict__ hbuf, const int* __restrict__ off,
    const int* __restrict__ csr_src, const float* __restrict__ bias,
    float* __restrict__ xout) {
  const int wave = (blockIdx.x * blockDim.x + threadIdx.x) >> 6;
  const int lane = threadIdx.x & 63;
  if (wave >= NN) return;
  const int n = wave;
  const int start = off[n], end = off[n + 1];
  const int HC = H * C;

  float adh[H];
#pragma unroll
  for (int h = 0; h < H; ++h) adh[h] = a_d[n * H + h];

  // pass 1a: segment max per head
  float mx[H];
#pragma unroll
  for (int h = 0; h < H; ++h) mx[h] = -1e30f;
  for (int j = start + lane; j < end; j += 64) {
#pragma unroll
    for (int h = 0; h < H; ++h) {
      float al = a_se[(size_t)j * H + h] + adh[h];
      al = al > 0.f ? al : 0.2f * al;
      mx[h] = fmaxf(mx[h], al);
    }
  }
#pragma unroll
  for (int s = 32; s > 0; s >>= 1)
#pragma unroll
    for (int h = 0; h < H; ++h) mx[h] = fmaxf(mx[h], __shfl_xor(mx[h], s));

  // pass 1b: denominator
  float sm[H];
#pragma unroll
  for (int h = 0; h < H; ++h) sm[h] = 0.f;
  for (int j = start + lane; j < end; j += 64) {
#pragma unroll
    for (int h = 0; h < H; ++h) {
      float al = a_se[(size_t)j * H + h] + adh[h];
      al = al > 0.f ? al : 0.2f * al;
      sm[h] += __expf(al - mx[h]);
    }
  }
#pragma unroll
  for (int s = 32; s > 0; s >>= 1)
#pragma unroll
    for (int h = 0; h < H; ++h) sm[h] += __shfl_xor(sm[h], s);
  float rd[H];
#pragma unroll
  for (int h = 0; h < H; ++h) rd[h] = 1.f / sm[h];

  // pass 2: weighted accumulate of h[src]
  float acc[KC] = {};
  if (PERLANE) {
    const int my_h = (lane * KC) / C;  // single head per lane
    float my_ad = adh[0], my_mx = mx[0], my_rd = rd[0];
#pragma unroll
    for (int h = 1; h < H; ++h)
      if (my_h == h) { my_ad = adh[h]; my_mx = mx[h]; my_rd = rd[h]; }
    for (int j = start; j < end; ++j) {
      int srcn = csr_src[j];
      float al = a_se[(size_t)j * H + my_h] + my_ad;
      al = al > 0.f ? al : 0.2f * al;
      float w = __expf(al - my_mx) * my_rd;
      const float4 hv =
          *reinterpret_cast<const float4*>(&hbuf[(size_t)srcn * HC + lane * 4]);
      acc[0] += w * hv.x; acc[1] += w * hv.y; acc[2] += w * hv.z; acc[3] += w * hv.w;
    }
    float4 o;
    o.x = fmaxf(acc[0] + bias[lane * 4 + 0], 0.f);
    o.y = fmaxf(acc[1] + bias[lane * 4 + 1], 0.f);
    o.z = fmaxf(acc[2] + bias[lane * 4 + 2], 0.f);
    o.w = fmaxf(acc[3] + bias[lane * 4 + 3], 0.f);
    *reinterpret_cast<float4*>(&xout[(size_t)n * HC + lane * 4]) = o;
  } else {
    // f = k*64 + lane, head = k (requires C == 64, KC == H)
    for (int j = start; j < end; ++j) {
      int srcn = csr_src[j];
      const float* hrow = &hbuf[(size_t)srcn * HC];
#pragma unroll
      for (int k = 0; k < KC; ++k) {
        float al = a_se[(size_t)j * H + k] + adh[k];
        al = al > 0.f ? al : 0.2f * al;
        float w = __expf(al - mx[k]) * rd[k];
        acc[k] += w * hrow[k * 64 + lane];
      }
    }
#pragma unroll
    for (int k = 0; k < KC; ++k) {
      int f = k * 64 + lane;
      xout[(size_t)n * HC + f] = fmaxf(acc[k] + bias[f], 0.f);
    }
  }
}

// ---------------------------------------------------------------------------
// Final head: sigmoid(concat(x1,x2,x3) @ Wf + bf). One wave per node.
// ---------------------------------------------------------------------------
__global__ void final_kernel(const float* __restrict__ x1, const float* __restrict__ x2,
                             const float* __restrict__ x3, const float* __restrict__ Wf,
                             const float* __restrict__ bf, float* __restrict__ out) {
  const int wave = (blockIdx.x * blockDim.x + threadIdx.x) >> 6;
  const int lane = threadIdx.x & 63;
  if (wave >= NN) return;
  float acc = 0.f;
  for (int f = lane; f < 1280; f += 64) {
    float v = (f < 256)   ? x1[(size_t)wave * 256 + f]
              : (f < 512) ? x2[(size_t)wave * 256 + (f - 256)]
                          : x3[(size_t)wave * 768 + (f - 512)];
    acc += v * Wf[f];
  }
#pragma unroll
  for (int s = 32; s > 0; s >>= 1) acc += __shfl_xor(acc, s);
  if (lane == 0) out[wave] = 1.f / (1.f + __expf(-(acc + bf[0])));
}

// ---------------------------------------------------------------------------

extern "C" void kernel_launch(void* const* d_in, const int* in_sizes, int n_in,
                              void* d_out, int out_size, void* d_ws, size_t ws_size,
                              hipStream_t stream) {
  const float* x     = (const float*)d_in[0];
  const int*   eidx  = (const int*)d_in[1];
  const float* eattr = (const float*)d_in[2];
  const float* W[3]   = {(const float*)d_in[3],  (const float*)d_in[9],  (const float*)d_in[15]};
  const float* ats[3] = {(const float*)d_in[4],  (const float*)d_in[10], (const float*)d_in[16]};
  const float* atd[3] = {(const float*)d_in[5],  (const float*)d_in[11], (const float*)d_in[17]};
  const float* We[3]  = {(const float*)d_in[6],  (const float*)d_in[12], (const float*)d_in[18]};
  const float* ate[3] = {(const float*)d_in[7],  (const float*)d_in[13], (const float*)d_in[19]};
  const float* bb[3]  = {(const float*)d_in[8],  (const float*)d_in[14], (const float*)d_in[20]};
  const float* Wf = (const float*)d_in[21];
  const float* bf = (const float*)d_in[22];
  float* out = (float*)d_out;

  const int* src = eidx;
  const int* dst = eidx + EE;

  char* p = (char*)d_ws;
  auto carve = [&](size_t bytes) -> char* {
    char* q = p;
    p += (bytes + 255) & ~(size_t)255;
    return q;
  };
  float* x1    = (float*)carve((size_t)NN * 256 * 4);
  float* x2    = (float*)carve((size_t)NN * 256 * 4);
  float* x3    = (float*)carve((size_t)NN * 768 * 4);
  float* hbuf  = (float*)carve((size_t)NN * 768 * 4);
  float* a_s   = (float*)carve((size_t)NN * 12 * 4);
  float* a_d   = (float*)carve((size_t)NN * 12 * 4);
  float* a_se  = (float*)carve((size_t)EF * 12 * 4);
  float* mea   = (float*)carve((size_t)NN * EDIM * 4);
  float* wec   = (float*)carve((size_t)EDIM * 12 * 4);
  int* cnt     = (int*)carve((size_t)NN * 4);
  int* off     = (int*)carve((size_t)(NN + 1) * 4);
  int* cursor  = (int*)carve((size_t)NN * 4);
  int* csr_src = (int*)carve((size_t)EF * 4);
  int* csr_eid = (int*)carve((size_t)EF * 4);

  // ---- graph structure (recomputed every call; deterministic inputs) ----
  hipMemsetAsync(cnt, 0, (size_t)NN * 4, stream);
  count_deg_kernel<<<(EE + 255) / 256, 256, 0, stream>>>(dst, cnt);
  scan_kernel<<<1, 1024, 0, stream>>>(cnt, off, cursor);
  scatter_kernel<<<(EF + 255) / 256, 256, 0, stream>>>(src, dst, cursor, csr_src, csr_eid);
  mean_ea_kernel<<<(NN * EDIM + 255) / 256, 256, 0, stream>>>(off, csr_eid, cnt, eattr, mea);

  const int Hs[3] = {8, 8, 12};
  const int Cs[3] = {32, 32, 64};
  const int Ks[3] = {16, 256, 256};
  const float* xin[3] = {x, x1, x2};
  float* xout[3] = {x1, x2, x3};

  for (int L = 0; L < 3; ++L) {
    const int H = Hs[L], C = Cs[L], K = Ks[L], HC = H * C;
    // h = xin @ W
    dim3 g(HC / 64, (NN + 63) / 64);
    gemm_kernel<<<g, 256, 0, stream>>>(xin[L], W[L], hbuf, NN, K, HC);
    // a_s, a_d
    asd_kernel<<<(NN * H + 255) / 256, 256, 0, stream>>>(hbuf, ats[L], atd[L], a_s, a_d, H, C);
    // We pre-contraction, then per-edge a_se
    wecomb_kernel<<<(EDIM * H + 255) / 256, 256, 0, stream>>>(We[L], ate[L], wec, H, C);
    ase_kernel<<<(EF * H + 255) / 256, 256, 0, stream>>>(csr_eid, csr_src, eattr, mea, wec,
                                                         a_s, a_se, H);
    // aggregation (softmax + gather) + bias + relu
    int blocks = (NN * 64 + 255) / 256;
    if (H == 8)
      gat_aggregate_kernel<8, 32, 4, true><<<blocks, 256, 0, stream>>>(
          a_se, a_d, hbuf, off, csr_src, bb[L], xout[L]);
    else
      gat_aggregate_kernel<12, 64, 12, false><<<blocks, 256, 0, stream>>>(
          a_se, a_d, hbuf, off, csr_src, bb[L], xout[L]);
  }

  final_kernel<<<(NN * 64 + 255) / 256, 256, 0, stream>>>(x1, x2, x3, Wf, bf, out);
}

// Round 2
// 608.825 us; speedup vs baseline: 1.2573x; 1.2573x over previous
//
#include <hip/hip_runtime.h>

#define NN 20000
#define EE 320000
#define EF 340000   /* EE + NN self loops */
#define EDIM 22

typedef short bf16x8 __attribute__((ext_vector_type(8)));
typedef float f32x4 __attribute__((ext_vector_type(4)));

__device__ __forceinline__ float b2f(ushort u) {
  union { unsigned u; float f; } v;
  v.u = ((unsigned)u) << 16;
  return v.f;
}
__device__ __forceinline__ ushort f2b(float f) {
  union { float f; unsigned u; } v;
  v.f = f;
  unsigned u = v.u;
  return (ushort)((u + 0x7fffu + ((u >> 16) & 1u)) >> 16);  // RNE
}

// ---------------------------------------------------------------------------
// Graph setup: CSR by dst (counting sort), mean edge_attr for self loops
// ---------------------------------------------------------------------------

__global__ void count_deg_kernel(const int* __restrict__ dst, int* __restrict__ cnt) {
  int e = blockIdx.x * blockDim.x + threadIdx.x;
  if (e < EE) atomicAdd(&cnt[dst[e]], 1);
}

// single-block scan of (cnt[i]+1) over NN elements -> exclusive offsets
__global__ void scan_kernel(const int* __restrict__ cnt, int* __restrict__ off,
                            int* __restrict__ cursor) {
  __shared__ int wsum[16];
  __shared__ int carry_s;
  const int tid = threadIdx.x, lane = tid & 63, w = tid >> 6;
  if (tid == 0) carry_s = 0;
  __syncthreads();
  for (int base = 0; base < NN; base += 1024) {
    int i = base + tid;
    int v = (i < NN) ? (cnt[i] + 1) : 0;
    int x = v;
#pragma unroll
    for (int s = 1; s < 64; s <<= 1) {
      int t = __shfl_up(x, s);
      if (lane >= s) x += t;
    }
    if (lane == 63) wsum[w] = x;
    __syncthreads();
    if (w == 0) {
      int ws = (lane < 16) ? wsum[lane] : 0;
#pragma unroll
      for (int s = 1; s < 16; s <<= 1) {
        int t = __shfl_up(ws, s);
        if (lane >= s) ws += t;
      }
      if (lane < 16) wsum[lane] = ws;
    }
    __syncthreads();
    int wbase = (w == 0) ? 0 : wsum[w - 1];
    int total = wsum[15];
    int excl = carry_s + wbase + x - v;
    if (i < NN) { off[i] = excl; cursor[i] = excl; }
    __syncthreads();
    if (tid == 0) carry_s += total;
    __syncthreads();
  }
  if (threadIdx.x == 0) off[NN] = carry_s;
}

__global__ void scatter_kernel(const int* __restrict__ src, const int* __restrict__ dst,
                               int* __restrict__ cursor, int* __restrict__ csr_src,
                               int* __restrict__ csr_eid) {
  int e = blockIdx.x * blockDim.x + threadIdx.x;
  if (e >= EF) return;
  int s, d;
  if (e < EE) { s = src[e]; d = dst[e]; } else { s = e - EE; d = s; }
  int pos = atomicAdd(&cursor[d], 1);
  csr_src[pos] = s;
  csr_eid[pos] = e;
}

__global__ void mean_ea_kernel(const int* __restrict__ off, const int* __restrict__ csr_eid,
                               const int* __restrict__ cnt, const float* __restrict__ edge_attr,
                               float* __restrict__ mean_ea) {
  int t = blockIdx.x * blockDim.x + threadIdx.x;
  if (t >= NN * EDIM) return;
  int n = t / EDIM, d = t % EDIM;
  int s = off[n], e = off[n + 1];
  float sum = 0.f;
  for (int j = s; j < e; ++j) {
    int eid = csr_eid[j];
    if (eid < EE) sum += edge_attr[(size_t)eid * EDIM + d];
  }
  mean_ea[t] = sum / fmaxf((float)cnt[n], 1.f);
}

// ---------------------------------------------------------------------------
// dtype conversions
// ---------------------------------------------------------------------------

// x [NN][16] f32 -> Abf [NN][32] bf16 (zero-padded K)
__global__ void cvt_x_kernel(const float* __restrict__ x, ushort* __restrict__ ab) {
  int t = blockIdx.x * blockDim.x + threadIdx.x;
  if (t >= NN * 32) return;
  int n = t >> 5, c = t & 31;
  ab[t] = (c < 16) ? f2b(x[n * 16 + c]) : (ushort)0;
}

// W [K][HC] f32 -> Wt [HC][Kp] bf16 (transpose + zero-pad K to Kp)
__global__ void cvt_w_kernel(const float* __restrict__ W, ushort* __restrict__ Wt,
                             int K, int Kp, int HC) {
  int t = blockIdx.x * blockDim.x + threadIdx.x;
  if (t >= HC * Kp) return;
  int nc = t / Kp, k = t % Kp;
  Wt[t] = (k < K) ? f2b(W[(size_t)k * HC + nc]) : (ushort)0;
}

// ---------------------------------------------------------------------------
// bf16 MFMA GEMM: C[M,Nc] = A[M,K] @ Bt[Nc,K]^T, all bf16, f32 accum.
// Block = 4 waves; wave computes 16 rows x 64 cols. K % 32 == 0, Nc % 64 == 0.
// A/B fragments loaded directly from global (16B contiguous per lane);
// W is small and L1/L2-resident, A is streamed.
// ---------------------------------------------------------------------------
__global__ __launch_bounds__(256) void mfma_gemm_kernel(
    const ushort* __restrict__ A, const ushort* __restrict__ Bt,
    ushort* __restrict__ C, int M, int K, int Nc) {
  const int lane = threadIdx.x & 63;
  const int wid = threadIdx.x >> 6;
  const int bm = blockIdx.y * 64 + wid * 16;
  const int bn = blockIdx.x * 64;
  const int r = lane & 15;   // A-row / B-col within 16
  const int kg = lane >> 4;  // k-group (8 bf16 each)

  f32x4 acc[4] = {};
  const int arow = bm + r;
  const bool aval = arow < M;
  const ushort* aptr = A + (size_t)arow * K + kg * 8;
  const ushort* bptr = Bt + (size_t)(bn + r) * K + kg * 8;

  for (int k0 = 0; k0 < K; k0 += 32) {
    bf16x8 af = {};
    if (aval) af = *(const bf16x8*)(aptr + k0);
#pragma unroll
    for (int nf = 0; nf < 4; ++nf) {
      bf16x8 bfr = *(const bf16x8*)(bptr + (size_t)nf * 16 * K + k0);
      acc[nf] = __builtin_amdgcn_mfma_f32_16x16x32_bf16(af, bfr, acc[nf], 0, 0, 0);
    }
  }
  // D mapping: col = bn + nf*16 + (lane&15), row = bm + (lane>>4)*4 + reg
#pragma unroll
  for (int nf = 0; nf < 4; ++nf) {
#pragma unroll
    for (int reg = 0; reg < 4; ++reg) {
      int row = bm + kg * 4 + reg;
      if (row < M) C[(size_t)row * Nc + bn + nf * 16 + r] = f2b(acc[nf][reg]);
    }
  }
}

// ---------------------------------------------------------------------------
// a_s / a_d from bf16 h
// ---------------------------------------------------------------------------
__global__ void asd_kernel(const ushort* __restrict__ h, const float* __restrict__ atts,
                           const float* __restrict__ attd, float* __restrict__ a_s,
                           float* __restrict__ a_d, int H, int C) {
  int t = blockIdx.x * blockDim.x + threadIdx.x;
  if (t >= NN * H) return;
  int n = t / H, hh = t % H;
  const ushort* row = h + (size_t)n * H * C + (size_t)hh * C;
  float s = 0.f, d = 0.f;
  for (int c = 0; c < C; c += 2) {
    unsigned u = *(const unsigned*)(row + c);
    float v0 = b2f((ushort)(u & 0xffff));
    float v1 = b2f((ushort)(u >> 16));
    s += v0 * atts[hh * C + c] + v1 * atts[hh * C + c + 1];
    d += v0 * attd[hh * C + c] + v1 * attd[hh * C + c + 1];
  }
  a_s[t] = s;
  a_d[t] = d;
}

// wecomb[d,h] = sum_c We[d, h*C+c] * att_e[h*C+c]
__global__ void wecomb_kernel(const float* __restrict__ We, const float* __restrict__ atte,
                              float* __restrict__ wec, int H, int C) {
  int t = blockIdx.x * blockDim.x + threadIdx.x;
  if (t >= EDIM * H) return;
  int d = t / H, hh = t % H;
  float v = 0.f;
  for (int c = 0; c < C; ++c) v += We[(size_t)d * H * C + hh * C + c] * atte[hh * C + c];
  wec[t] = v;
}

// a_se[j,h] = a_e(edge j) + a_s[src(j),h], in CSR order
__global__ void ase_kernel(const int* __restrict__ csr_eid, const int* __restrict__ csr_src,
                           const float* __restrict__ edge_attr, const float* __restrict__ mean_ea,
                           const float* __restrict__ wec, const float* __restrict__ a_s,
                           float* __restrict__ a_se, int H) {
  int t = blockIdx.x * blockDim.x + threadIdx.x;
  if (t >= EF * H) return;
  int j = t / H, hh = t % H;
  int eid = csr_eid[j];
  const float* ea = (eid < EE) ? &edge_attr[(size_t)eid * EDIM]
                               : &mean_ea[(size_t)(eid - EE) * EDIM];
  float v = 0.f;
#pragma unroll
  for (int d = 0; d < EDIM; ++d) v += ea[d] * wec[d * H + hh];
  a_se[t] = v + a_s[csr_src[j] * H + hh];
}

// ---------------------------------------------------------------------------
// Per-node aggregation: one wave per node; segment softmax + bf16 gather.
// Lane owns FPL contiguous features f0 = lane*FPL (FPL = H*C/64).
// ---------------------------------------------------------------------------
template <int H, int C, int FPL>
__global__ __launch_bounds__(256) void gat_aggregate_kernel(
    const float* __restrict__ a_se, const float* __restrict__ a_d,
    const ushort* __restrict__ hb, const int* __restrict__ off,
    const int* __restrict__ csr_src, const float* __restrict__ bias,
    float* __restrict__ xout, ushort* __restrict__ xout_b) {
  const int n = (int)((blockIdx.x * blockDim.x + threadIdx.x) >> 6);
  const int lane = threadIdx.x & 63;
  if (n >= NN) return;
  const int start = off[n], end = off[n + 1];
  constexpr int HC = H * C;

  float adh[H];
#pragma unroll
  for (int h = 0; h < H; ++h) adh[h] = a_d[n * H + h];

  // pass 1a: segment max per head
  float mx[H];
#pragma unroll
  for (int h = 0; h < H; ++h) mx[h] = -1e30f;
  for (int j = start + lane; j < end; j += 64) {
    const float4* ap = (const float4*)(a_se + (size_t)j * H);
#pragma unroll
    for (int q = 0; q < H / 4; ++q) {
      float4 v = ap[q];
      float vv[4] = {v.x, v.y, v.z, v.w};
#pragma unroll
      for (int e = 0; e < 4; ++e) {
        int h = q * 4 + e;
        float al = vv[e] + adh[h];
        al = al > 0.f ? al : 0.2f * al;
        mx[h] = fmaxf(mx[h], al);
      }
    }
  }
#pragma unroll
  for (int s = 32; s > 0; s >>= 1)
#pragma unroll
    for (int h = 0; h < H; ++h) mx[h] = fmaxf(mx[h], __shfl_xor(mx[h], s));

  // pass 1b: denominator
  float sm[H];
#pragma unroll
  for (int h = 0; h < H; ++h) sm[h] = 0.f;
  for (int j = start + lane; j < end; j += 64) {
    const float4* ap = (const float4*)(a_se + (size_t)j * H);
#pragma unroll
    for (int q = 0; q < H / 4; ++q) {
      float4 v = ap[q];
      float vv[4] = {v.x, v.y, v.z, v.w};
#pragma unroll
      for (int e = 0; e < 4; ++e) {
        int h = q * 4 + e;
        float al = vv[e] + adh[h];
        al = al > 0.f ? al : 0.2f * al;
        sm[h] += __expf(al - mx[h]);
      }
    }
  }
#pragma unroll
  for (int s = 32; s > 0; s >>= 1)
#pragma unroll
    for (int h = 0; h < H; ++h) sm[h] += __shfl_xor(sm[h], s);
  float rd[H];
#pragma unroll
  for (int h = 0; h < H; ++h) rd[h] = 1.f / sm[h];

  // pass 2: weighted gather-accumulate of bf16 h[src]
  constexpr bool ONE_HEAD = (C % FPL) == 0;  // lane's slice never crosses a head
  const int f0 = lane * FPL;
  const int hA = f0 / C;
  const int hB = ONE_HEAD ? hA : (f0 + FPL - 1) / C;
  const int split = ONE_HEAD ? FPL : min(FPL, (hA + 1) * C - f0);
  const float adA = adh[hA], mxA = mx[hA], rdA = rd[hA];
  const float adB = adh[hB], mxB = mx[hB], rdB = rd[hB];

  float acc[FPL] = {};
  for (int j = start; j < end; ++j) {
    int srcn = csr_src[j];
    float aA = a_se[(size_t)j * H + hA] + adA;
    aA = aA > 0.f ? aA : 0.2f * aA;
    float wA = __expf(aA - mxA) * rdA;
    float wB = wA;
    if (!ONE_HEAD && hB != hA) {
      float aB = a_se[(size_t)j * H + hB] + adB;
      aB = aB > 0.f ? aB : 0.2f * aB;
      wB = __expf(aB - mxB) * rdB;
    }
    const ushort* hrow = hb + (size_t)srcn * HC + f0;
#pragma unroll
    for (int q = 0; q < FPL / 4; ++q) {
      uint2 u = *(const uint2*)(hrow + q * 4);
      unsigned uu[2] = {u.x, u.y};
#pragma unroll
      for (int e = 0; e < 2; ++e) {
        int i = q * 4 + e * 2;
        float v0 = b2f((ushort)(uu[e] & 0xffff));
        float v1 = b2f((ushort)(uu[e] >> 16));
        acc[i] += (i < split ? wA : wB) * v0;
        acc[i + 1] += (i + 1 < split ? wA : wB) * v1;
      }
    }
  }
  // bias + relu + stores (f32 always, bf16 if requested)
#pragma unroll
  for (int i = 0; i < FPL; ++i) acc[i] = fmaxf(acc[i] + bias[f0 + i], 0.f);
#pragma unroll
  for (int q = 0; q < FPL / 4; ++q) {
    float4 o = make_float4(acc[q * 4], acc[q * 4 + 1], acc[q * 4 + 2], acc[q * 4 + 3]);
    *(float4*)(xout + (size_t)n * HC + f0 + q * 4) = o;
  }
  if (xout_b) {
#pragma unroll
    for (int q = 0; q < FPL / 2; ++q) {
      unsigned u = (unsigned)f2b(acc[q * 2]) | ((unsigned)f2b(acc[q * 2 + 1]) << 16);
      *(unsigned*)(xout_b + (size_t)n * HC + f0 + q * 2) = u;
    }
  }
}

// ---------------------------------------------------------------------------
// Final head: sigmoid(concat(x1,x2,x3) @ Wf + bf). One wave per node.
// ---------------------------------------------------------------------------
__global__ void final_kernel(const float* __restrict__ x1, const float* __restrict__ x2,
                             const float* __restrict__ x3, const float* __restrict__ Wf,
                             const float* __restrict__ bf, float* __restrict__ out) {
  const int wave = (int)((blockIdx.x * blockDim.x + threadIdx.x) >> 6);
  const int lane = threadIdx.x & 63;
  if (wave >= NN) return;
  float acc = 0.f;
  for (int f = lane; f < 1280; f += 64) {
    float v = (f < 256)   ? x1[(size_t)wave * 256 + f]
              : (f < 512) ? x2[(size_t)wave * 256 + (f - 256)]
                          : x3[(size_t)wave * 768 + (f - 512)];
    acc += v * Wf[f];
  }
#pragma unroll
  for (int s = 32; s > 0; s >>= 1) acc += __shfl_xor(acc, s);
  if (lane == 0) out[wave] = 1.f / (1.f + __expf(-(acc + bf[0])));
}

// ---------------------------------------------------------------------------

extern "C" void kernel_launch(void* const* d_in, const int* in_sizes, int n_in,
                              void* d_out, int out_size, void* d_ws, size_t ws_size,
                              hipStream_t stream) {
  const float* x     = (const float*)d_in[0];
  const int*   eidx  = (const int*)d_in[1];
  const float* eattr = (const float*)d_in[2];
  const float* W[3]   = {(const float*)d_in[3],  (const float*)d_in[9],  (const float*)d_in[15]};
  const float* ats[3] = {(const float*)d_in[4],  (const float*)d_in[10], (const float*)d_in[16]};
  const float* atd[3] = {(const float*)d_in[5],  (const float*)d_in[11], (const float*)d_in[17]};
  const float* We[3]  = {(const float*)d_in[6],  (const float*)d_in[12], (const float*)d_in[18]};
  const float* ate[3] = {(const float*)d_in[7],  (const float*)d_in[13], (const float*)d_in[19]};
  const float* bb[3]  = {(const float*)d_in[8],  (const float*)d_in[14], (const float*)d_in[20]};
  const float* Wf = (const float*)d_in[21];
  const float* bf = (const float*)d_in[22];
  float* out = (float*)d_out;

  const int* src = eidx;
  const int* dst = eidx + EE;

  char* p = (char*)d_ws;
  auto carve = [&](size_t bytes) -> char* {
    char* q = p;
    p += (bytes + 255) & ~(size_t)255;
    return q;
  };
  float*  x1    = (float*)carve((size_t)NN * 256 * 4);
  float*  x2    = (float*)carve((size_t)NN * 256 * 4);
  float*  x3    = (float*)carve((size_t)NN * 768 * 4);
  ushort* x1b   = (ushort*)carve((size_t)NN * 256 * 2);
  ushort* x2b   = (ushort*)carve((size_t)NN * 256 * 2);
  ushort* hbuf  = (ushort*)carve((size_t)NN * 768 * 2);
  ushort* abf1  = (ushort*)carve((size_t)NN * 32 * 2);
  ushort* wt1   = (ushort*)carve((size_t)256 * 32 * 2);
  ushort* wt2   = (ushort*)carve((size_t)256 * 256 * 2);
  ushort* wt3   = (ushort*)carve((size_t)768 * 256 * 2);
  float*  a_s   = (float*)carve((size_t)NN * 12 * 4);
  float*  a_d   = (float*)carve((size_t)NN * 12 * 4);
  float*  a_se  = (float*)carve((size_t)EF * 12 * 4);
  float*  mea   = (float*)carve((size_t)NN * EDIM * 4);
  float*  wec   = (float*)carve((size_t)EDIM * 12 * 4);
  int* cnt      = (int*)carve((size_t)NN * 4);
  int* off      = (int*)carve((size_t)(NN + 1) * 4);
  int* cursor   = (int*)carve((size_t)NN * 4);
  int* csr_src  = (int*)carve((size_t)EF * 4);
  int* csr_eid  = (int*)carve((size_t)EF * 4);

  // ---- graph structure (recomputed every call; deterministic inputs) ----
  hipMemsetAsync(cnt, 0, (size_t)NN * 4, stream);
  count_deg_kernel<<<(EE + 255) / 256, 256, 0, stream>>>(dst, cnt);
  scan_kernel<<<1, 1024, 0, stream>>>(cnt, off, cursor);
  scatter_kernel<<<(EF + 255) / 256, 256, 0, stream>>>(src, dst, cursor, csr_src, csr_eid);
  mean_ea_kernel<<<(NN * EDIM + 255) / 256, 256, 0, stream>>>(off, csr_eid, cnt, eattr, mea);

  // ---- dtype prep ----
  cvt_x_kernel<<<(NN * 32 + 255) / 256, 256, 0, stream>>>(x, abf1);
  cvt_w_kernel<<<(256 * 32 + 255) / 256, 256, 0, stream>>>(W[0], wt1, 16, 32, 256);
  cvt_w_kernel<<<(256 * 256 + 255) / 256, 256, 0, stream>>>(W[1], wt2, 256, 256, 256);
  cvt_w_kernel<<<(768 * 256 + 255) / 256, 256, 0, stream>>>(W[2], wt3, 256, 256, 768);

  const int Hs[3] = {8, 8, 12};
  const int Cs[3] = {32, 32, 64};
  const int Kp[3] = {32, 256, 256};
  const ushort* Ain[3] = {abf1, x1b, x2b};
  const ushort* Wt[3] = {wt1, wt2, wt3};
  float* xoutf[3] = {x1, x2, x3};
  ushort* xoutb[3] = {x1b, x2b, nullptr};

  for (int L = 0; L < 3; ++L) {
    const int H = Hs[L], C = Cs[L], HC = H * C;
    // h = A @ Wt^T  (bf16 MFMA)
    dim3 g(HC / 64, (NN + 63) / 64);
    mfma_gemm_kernel<<<g, 256, 0, stream>>>(Ain[L], Wt[L], hbuf, NN, Kp[L], HC);
    // a_s, a_d
    asd_kernel<<<(NN * H + 255) / 256, 256, 0, stream>>>(hbuf, ats[L], atd[L], a_s, a_d, H, C);
    // We pre-contraction, then per-edge a_se
    wecomb_kernel<<<(EDIM * H + 255) / 256, 256, 0, stream>>>(We[L], ate[L], wec, H, C);
    ase_kernel<<<(EF * H + 255) / 256, 256, 0, stream>>>(csr_eid, csr_src, eattr, mea, wec,
                                                         a_s, a_se, H);
    // aggregation (softmax + gather) + bias + relu
    int blocks = (NN * 64 + 255) / 256;
    if (H == 8)
      gat_aggregate_kernel<8, 32, 4><<<blocks, 256, 0, stream>>>(
          a_se, a_d, hbuf, off, csr_src, bb[L], xoutf[L], xoutb[L]);
    else
      gat_aggregate_kernel<12, 64, 12><<<blocks, 256, 0, stream>>>(
          a_se, a_d, hbuf, off, csr_src, bb[L], xoutf[L], xoutb[L]);
  }

  final_kernel<<<(NN * 64 + 255) / 256, 256, 0, stream>>>(x1, x2, x3, Wf, bf, out);
}